// Round 4
// baseline (223.856 us; speedup 1.0000x reference)
//
#include <hip/hip_runtime.h>
#include <hip/hip_bf16.h>
#include <stdint.h>

// GATv2-style layer, MI355X. 6 kernels:
//  k_convert: x,W fp32 -> bf16
//  k_pack:    adj int32 -> bitmask (2 MB) + zero stats
//  k_gemm:    Wh = x @ W^T (bf16 MFMA) -> WhT bf16 (LDS transpose) + s_src/s_dst
//  k_attn:    fused masked-softmax numer/denom + PV MFMA, 8 j-slices.
//             16 rows/wave (acc=16 regs) keeps total regs <=64 incl AGPRs
//             (gfx950 unified file) -> 8 waves/SIMD to hide L2/exp latency.
//  k_stats:   column sums of h' = (sum num)/(sum l) via atomics; writes linv
//  k_apply:   recompute h', apply layernorm + relu
// num (33.5 MB, bf16) aliases xb/wb which are dead after k_gemm.

typedef __attribute__((ext_vector_type(4))) float f32x4;
typedef __attribute__((ext_vector_type(8))) short s16x8;

#define LOG2E 1.4426950408889634f

static __device__ __forceinline__ ushort f2bf(float f) {
  union { float f; uint32_t u; } v; v.f = f;
  uint32_t r = (v.u + 0x7FFFu + ((v.u >> 16) & 1u)) >> 16;  // RNE
  return (ushort)r;
}

static __device__ __forceinline__ short bf16b(float f) {
  __hip_bfloat16 h = __float2bfloat16(f);
  union { __hip_bfloat16 h; short s; } c; c.h = h;
  return c.s;
}

static __device__ __forceinline__ float bf2f(ushort u) {
  union { uint32_t u; float f; } c; c.u = ((uint32_t)u) << 16;
  return c.f;
}

__global__ __launch_bounds__(256) void k_convert(const float* __restrict__ x,
                                                 const float* __restrict__ W,
                                                 ushort* __restrict__ xb,
                                                 ushort* __restrict__ wb) {
  const int idx = (blockIdx.x * 256 + threadIdx.x) * 4;
  const int NX = 4096 * 512;
  if (idx < NX) {
    float4 v = *(const float4*)(x + idx);
    ushort4 o; o.x = f2bf(v.x); o.y = f2bf(v.y); o.z = f2bf(v.z); o.w = f2bf(v.w);
    *(ushort4*)(xb + idx) = o;
  } else {
    const int k = idx - NX;
    float4 v = *(const float4*)(W + k);
    ushort4 o; o.x = f2bf(v.x); o.y = f2bf(v.y); o.z = f2bf(v.z); o.w = f2bf(v.w);
    *(ushort4*)(wb + k) = o;
  }
}

// adj[4096][4096] int32 -> maskw[4096*64] u64 (bit j&63 of word j>>6); zero stats.
__global__ __launch_bounds__(256) void k_pack(const int* __restrict__ adj,
                                              unsigned long long* __restrict__ maskw,
                                              float* __restrict__ stats) {
  const int t = threadIdx.x;
  if (blockIdx.x == 0) {
    stats[t] = 0.f; stats[t + 256] = 0.f; stats[t + 512] = 0.f; stats[t + 768] = 0.f;
  }
  const size_t base = (size_t)blockIdx.x * 8192;
  const int lane = t & 63;
#pragma unroll 4
  for (int it = 0; it < 32; ++it) {
    const size_t elem = base + it * 256 + t;
    unsigned long long b = __ballot(adj[elem] > 0);
    if (lane == 0) maskw[elem >> 6] = b;
  }
}

// Per block: 64 rows (m0) x one head's 64 cols. K=512 direct-global MFMA.
// Epilogue: s_src/s_dst via shfl_xor reduce; WhT bf16 via LDS transpose.
__global__ __launch_bounds__(256) void k_gemm(const ushort* __restrict__ xb,
                                              const ushort* __restrict__ wb,
                                              const float* __restrict__ a,
                                              ushort* __restrict__ WhT,
                                              float* __restrict__ ssrcT,
                                              float* __restrict__ sdstT) {
  __shared__ float tl[64 * 65];
  const int lane = threadIdx.x & 63;
  const int wv = threadIdx.x >> 6;       // 4 waves: M sub-tiles
  const int l15 = lane & 15, lg = lane >> 4;
  const int m0 = blockIdx.x * 64;
  const int h = blockIdx.y;
  const int n0 = h * 64;
  const ushort* ap = xb + (size_t)(m0 + wv * 16 + l15) * 512 + lg * 8;
  f32x4 acc[4] = {};
  for (int k0 = 0; k0 < 512; k0 += 32) {
    s16x8 av = *(const s16x8*)(ap + k0);
#pragma unroll
    for (int ct = 0; ct < 4; ++ct) {
      s16x8 b = *(const s16x8*)(wb + (size_t)(n0 + ct * 16 + l15) * 512 + k0 + lg * 8);
      acc[ct] = __builtin_amdgcn_mfma_f32_16x16x32_bf16(av, b, acc[ct], 0, 0, 0);
    }
  }
  // ---- svec: s[row] = sum_col acc*a_slice, reduce over 16 l15 lanes ----
  float aS[4], aD[4];
#pragma unroll
  for (int ct = 0; ct < 4; ++ct) {
    aS[ct] = a[ct * 16 + l15];
    aD[ct] = a[64 + ct * 16 + l15];
  }
#pragma unroll
  for (int r = 0; r < 4; ++r) {
    float s1 = acc[0][r] * aS[0] + acc[1][r] * aS[1] + acc[2][r] * aS[2] + acc[3][r] * aS[3];
    float s2 = acc[0][r] * aD[0] + acc[1][r] * aD[1] + acc[2][r] * aD[2] + acc[3][r] * aD[3];
#pragma unroll
    for (int off = 1; off < 16; off <<= 1) {
      s1 += __shfl_xor(s1, off);
      s2 += __shfl_xor(s2, off);
    }
    if (l15 == 0) {
      const int row = m0 + wv * 16 + lg * 4 + r;
      ssrcT[h * 4096 + row] = s1 * LOG2E;
      sdstT[h * 4096 + row] = s2 * LOG2E;
    }
  }
  // ---- transposed bf16 store: WhT[n0+c][m0+m] ----
#pragma unroll
  for (int ct = 0; ct < 4; ++ct)
#pragma unroll
    for (int r = 0; r < 4; ++r)
      tl[(ct * 16 + l15) * 65 + wv * 16 + lg * 4 + r] = acc[ct][r];
  __syncthreads();
  const int c = threadIdx.x >> 2, mb = (threadIdx.x & 3) * 16;
  s16x8 o0, o1;
#pragma unroll
  for (int k = 0; k < 8; ++k) o0[k] = bf16b(tl[c * 65 + mb + k]);
#pragma unroll
  for (int k = 0; k < 8; ++k) o1[k] = bf16b(tl[c * 65 + mb + 8 + k]);
  *(s16x8*)(WhT + (size_t)(n0 + c) * 4096 + m0 + mb) = o0;
  *(s16x8*)(WhT + (size_t)(n0 + c) * 4096 + m0 + mb + 8) = o1;
}

// grid (8 j-slices, 256 i-chunks) = 2048 blocks, 512 thr = 8 waves = 8 heads.
// Wave: 16 rows x its head's 64 cols x 512 j. Total regs ~56 (incl 16 acc)
// -> 8 waves/SIMD; TLP hides L2 + trans latency.
__global__ __launch_bounds__(512, 8) void k_attn(
    const uint32_t* __restrict__ mask32,
    const ushort* __restrict__ WhT,
    const float* __restrict__ ssrcT,
    const float* __restrict__ sdstT,
    ushort* __restrict__ num,     // [8][4096][512] bf16
    float* __restrict__ lbuf) {   // [8][8][4096]
  const int lane = threadIdx.x & 63;
  const int h = threadIdx.x >> 6;  // wave == head
  const int l15 = lane & 15, lg = lane >> 4;
  const int jh = blockIdx.x;       // j-slice -> XCD affinity (round-robin)
  const int i0 = blockIdx.y * 16;
  const int jbase = jh * 512;

  const float sd = sdstT[h * 4096 + i0 + l15];
  const float* ssp = ssrcT + h * 4096 + jbase + lg * 8;
  const ushort* bp = WhT + (size_t)(h * 64 + l15) * 4096 + jbase + lg * 8;
  const uint32_t* mp = mask32 + (size_t)(i0 + l15) * 128 + (jbase >> 5);

  f32x4 acc[4] = {};
  float lacc = 0.f;

  for (int jb = 0; jb < 512; jb += 32) {
    const float4 u = *(const float4*)(ssp + jb);
    const float4 v = *(const float4*)(ssp + jb + 4);
    const uint32_t mm = mp[jb >> 5] >> (lg * 8);
    const s16x8 b0 = *(const s16x8*)(bp + jb);
    const s16x8 b1 = *(const s16x8*)(bp + jb + 16 * 4096);
    const s16x8 b2 = *(const s16x8*)(bp + jb + 32 * 4096);
    const s16x8 b3 = *(const s16x8*)(bp + jb + 48 * 4096);
    const float s8[8] = {u.x, u.y, u.z, u.w, v.x, v.y, v.z, v.w};
    s16x8 pa;
#pragma unroll
    for (int q = 0; q < 8; ++q) {
      float e = sd + s8[q]; e = fmaxf(e, 0.2f * e);
      float xq = __builtin_amdgcn_exp2f(e);
      float w = ((mm >> q) & 1) ? xq : 0.f;
      lacc += w; pa[q] = bf16b(w);
    }
    acc[0] = __builtin_amdgcn_mfma_f32_16x16x32_bf16(pa, b0, acc[0], 0, 0, 0);
    acc[1] = __builtin_amdgcn_mfma_f32_16x16x32_bf16(pa, b1, acc[1], 0, 0, 0);
    acc[2] = __builtin_amdgcn_mfma_f32_16x16x32_bf16(pa, b2, acc[2], 0, 0, 0);
    acc[3] = __builtin_amdgcn_mfma_f32_16x16x32_bf16(pa, b3, acc[3], 0, 0, 0);
  }

  // denominator partial: reduce over the 4 lane-groups (bits 4,5 of lane)
  lacc += __shfl_xor(lacc, 16);
  lacc += __shfl_xor(lacc, 32);
  if (lane < 16) lbuf[((size_t)jh * 8 + h) * 4096 + i0 + lane] = lacc;

  ushort* np = num + (size_t)jh * 4096 * 512;
#pragma unroll
  for (int ct = 0; ct < 4; ++ct)
#pragma unroll
    for (int r = 0; r < 4; ++r)
      np[(size_t)(i0 + lg * 4 + r) * 512 + h * 64 + ct * 16 + l15] =
          (ushort)bf16b(acc[ct][r]);
}

// 256 blocks x 512 thr; block = 16 rows, thread = 1 col. linv shared via LDS.
__global__ __launch_bounds__(512) void k_stats(const ushort* __restrict__ num,
                                               const float* __restrict__ lbuf,
                                               float* __restrict__ linv,
                                               float* __restrict__ stats) {
  __shared__ float linv_s[128];
  const int t = threadIdx.x;
  const int r0 = blockIdx.x * 16;
  if (t < 128) {
    const int r = r0 + (t >> 3), hh = t & 7;
    float l = 0.f;
#pragma unroll
    for (int s = 0; s < 8; ++s) l += lbuf[((size_t)s * 8 + hh) * 4096 + r];
    const float inv = 1.0f / l;
    linv_s[t] = inv;
    linv[r * 8 + hh] = inv;
  }
  __syncthreads();
  const int c = t;
  const int hh = c >> 6;
  float s1 = 0.f, s2 = 0.f;
  for (int rr = 0; rr < 16; ++rr) {
    const int r = r0 + rr;
    float nsum = 0.f;
#pragma unroll
    for (int s = 0; s < 8; ++s)
      nsum += bf2f(num[(size_t)s * 4096 * 512 + (size_t)r * 512 + c]);
    const float v = nsum * linv_s[rr * 8 + hh];
    s1 += v; s2 += v * v;
  }
  atomicAdd(&stats[c], s1);
  atomicAdd(&stats[512 + c], s2);
}

// 1024 blocks x 256 thr; thread = 8 consecutive cols of one row.
__global__ __launch_bounds__(256) void k_apply(const ushort* __restrict__ num,
                                               const float* __restrict__ linv,
                                               const float* __restrict__ stats,
                                               const float* __restrict__ gamma,
                                               const float* __restrict__ beta,
                                               float* __restrict__ out) {
  const size_t idx8 = ((size_t)blockIdx.x * 256 + threadIdx.x) * 8;
  const int r = (int)(idx8 >> 9);
  const int c0 = (int)(idx8 & 511);
  const float li = linv[r * 8 + (c0 >> 6)];
  float nsum[8] = {};
#pragma unroll
  for (int s = 0; s < 8; ++s) {
    s16x8 nv = *(const s16x8*)(num + (size_t)s * 4096 * 512 + idx8);
#pragma unroll
    for (int k = 0; k < 8; ++k) nsum[k] += bf2f((ushort)nv[k]);
  }
#pragma unroll
  for (int k = 0; k < 8; ++k) {
    const int cc = c0 + k;
    const float mean = stats[cc] * (1.f / 4096.f);
    const float var = stats[512 + cc] * (1.f / 4096.f) - mean * mean;
    const float v = nsum[k] * li;
    const float val = (v - mean) * rsqrtf(var + 1e-5f) * gamma[cc] + beta[cc];
    out[idx8 + k] = fmaxf(val, 0.f);
  }
}

extern "C" void kernel_launch(void* const* d_in, const int* in_sizes, int n_in,
                              void* d_out, int out_size, void* d_ws, size_t ws_size,
                              hipStream_t stream) {
  const float* x = (const float*)d_in[0];
  const int* adj = (const int*)d_in[1];
  const float* W = (const float*)d_in[2];
  const float* a = (const float*)d_in[3];
  const float* gamma = (const float*)d_in[4];
  const float* beta = (const float*)d_in[5];
  float* out = (float*)d_out;

  char* ws = (char*)d_ws;
  size_t off = 0;
  auto alloc = [&](size_t bytes) -> void* {
    void* p = ws + off;
    off += (bytes + 255) & ~(size_t)255;
    return p;
  };
  // persistent region (~7.7 MB)
  ushort* WhT   = (ushort*)alloc((size_t)512 * 4096 * 2);
  float*  ssrcT = (float*)alloc((size_t)8 * 4096 * 4);
  float*  sdstT = (float*)alloc((size_t)8 * 4096 * 4);
  unsigned long long* maskw = (unsigned long long*)alloc((size_t)4096 * 64 * 8);
  float*  lbuf  = (float*)alloc((size_t)64 * 4096 * 4);
  float*  linv  = (float*)alloc((size_t)4096 * 8 * 4);
  float*  stats = (float*)alloc((size_t)1024 * 4);
  // overlay region: xb+wb (gemm inputs) aliased by num (attn output)
  const size_t ov = off;
  ushort* xb = (ushort*)(ws + ov);
  ushort* wb = (ushort*)(ws + ov + (size_t)4096 * 512 * 2);
  ushort* num = (ushort*)(ws + ov);           // [8][4096][512] bf16 = 33.5 MB
  // total ~41.2 MB

  hipLaunchKernelGGL(k_convert, dim3(2304), dim3(256), 0, stream, x, W, xb, wb);
  hipLaunchKernelGGL(k_pack, dim3(2048), dim3(256), 0, stream, adj, maskw, stats);
  hipLaunchKernelGGL(k_gemm, dim3(64, 8), dim3(256), 0, stream, xb, wb, a, WhT, ssrcT, sdstT);
  hipLaunchKernelGGL(k_attn, dim3(8, 256), dim3(512), 0, stream,
                     (const uint32_t*)maskw, WhT, ssrcT, sdstT, num, lbuf);
  hipLaunchKernelGGL(k_stats, dim3(256), dim3(512), 0, stream, num, lbuf, linv, stats);
  hipLaunchKernelGGL(k_apply, dim3(1024), dim3(256), 0, stream, num, linv, stats, gamma, beta, out);
}

// Round 5
// 106.819 us; speedup vs baseline: 2.0957x; 2.0957x over previous
//
#include <hip/hip_runtime.h>
#include <hip/hip_bf16.h>
#include <stdint.h>

// GATv2-style layer, MI355X. 6 kernels:
//  k_convert: x,W fp32 -> bf16
//  k_pack:    adj int32 -> bitmask (2 MB) + zero stats
//  k_gemm:    Wh = x @ W^T (bf16 MFMA) -> WhT bf16 (LDS transpose) + s_src/s_dst
//  k_attn:    fused masked-softmax numer/denom + PV MFMA.
//             Block = 1 head x 256 rows x 1024-j slice; all operands staged in
//             LDS (B-tile double-buffered via global_load_lds w/ pre-swizzled
//             source; mask + ss staged once) -> no dependent global loads in
//             the main loop. 512 blocks = 2 blocks/CU exactly.
//  k_stats:   column sums of h' = (sum num)/(sum l) via atomics; writes linv
//  k_apply:   recompute h', apply layernorm + relu
// num (16.8 MB, bf16, 4 j-slices) aliases xb/wb which are dead after k_gemm.

typedef __attribute__((ext_vector_type(4))) float f32x4;
typedef __attribute__((ext_vector_type(8))) short s16x8;

#define LOG2E 1.4426950408889634f

static __device__ __forceinline__ ushort f2bf(float f) {
  union { float f; uint32_t u; } v; v.f = f;
  uint32_t r = (v.u + 0x7FFFu + ((v.u >> 16) & 1u)) >> 16;  // RNE
  return (ushort)r;
}

static __device__ __forceinline__ short bf16b(float f) {
  __hip_bfloat16 h = __float2bfloat16(f);
  union { __hip_bfloat16 h; short s; } c; c.h = h;
  return c.s;
}

static __device__ __forceinline__ float bf2f(ushort u) {
  union { uint32_t u; float f; } c; c.u = ((uint32_t)u) << 16;
  return c.f;
}

// async global->LDS, 16B per lane; dest = wave-uniform base + lane*16
static __device__ __forceinline__ void gl_lds16(const ushort* g, ushort* l) {
  __builtin_amdgcn_global_load_lds(
      (const __attribute__((address_space(1))) unsigned int*)(g),
      (__attribute__((address_space(3))) unsigned int*)(l), 16, 0, 0);
}

__global__ __launch_bounds__(256) void k_convert(const float* __restrict__ x,
                                                 const float* __restrict__ W,
                                                 ushort* __restrict__ xb,
                                                 ushort* __restrict__ wb) {
  const int idx = (blockIdx.x * 256 + threadIdx.x) * 4;
  const int NX = 4096 * 512;
  if (idx < NX) {
    float4 v = *(const float4*)(x + idx);
    ushort4 o; o.x = f2bf(v.x); o.y = f2bf(v.y); o.z = f2bf(v.z); o.w = f2bf(v.w);
    *(ushort4*)(xb + idx) = o;
  } else {
    const int k = idx - NX;
    float4 v = *(const float4*)(W + k);
    ushort4 o; o.x = f2bf(v.x); o.y = f2bf(v.y); o.z = f2bf(v.z); o.w = f2bf(v.w);
    *(ushort4*)(wb + k) = o;
  }
}

// adj[4096][4096] int32 -> maskw[4096*64] u64 (bit j&63 of word j>>6); zero stats.
__global__ __launch_bounds__(256) void k_pack(const int* __restrict__ adj,
                                              unsigned long long* __restrict__ maskw,
                                              float* __restrict__ stats) {
  const int t = threadIdx.x;
  if (blockIdx.x == 0) {
    stats[t] = 0.f; stats[t + 256] = 0.f; stats[t + 512] = 0.f; stats[t + 768] = 0.f;
  }
  const size_t base = (size_t)blockIdx.x * 8192;
  const int lane = t & 63;
#pragma unroll 4
  for (int it = 0; it < 32; ++it) {
    const size_t elem = base + it * 256 + t;
    unsigned long long b = __ballot(adj[elem] > 0);
    if (lane == 0) maskw[elem >> 6] = b;
  }
}

// Per block: 64 rows (m0) x one head's 64 cols. K=512 direct-global MFMA.
// Epilogue: s_src/s_dst via shfl_xor reduce; WhT bf16 via LDS transpose.
__global__ __launch_bounds__(256) void k_gemm(const ushort* __restrict__ xb,
                                              const ushort* __restrict__ wb,
                                              const float* __restrict__ a,
                                              ushort* __restrict__ WhT,
                                              float* __restrict__ ssrcT,
                                              float* __restrict__ sdstT) {
  __shared__ float tl[64 * 65];
  const int lane = threadIdx.x & 63;
  const int wv = threadIdx.x >> 6;       // 4 waves: M sub-tiles
  const int l15 = lane & 15, lg = lane >> 4;
  const int m0 = blockIdx.x * 64;
  const int h = blockIdx.y;
  const int n0 = h * 64;
  const ushort* ap = xb + (size_t)(m0 + wv * 16 + l15) * 512 + lg * 8;
  f32x4 acc[4] = {};
  for (int k0 = 0; k0 < 512; k0 += 32) {
    s16x8 av = *(const s16x8*)(ap + k0);
#pragma unroll
    for (int ct = 0; ct < 4; ++ct) {
      s16x8 b = *(const s16x8*)(wb + (size_t)(n0 + ct * 16 + l15) * 512 + k0 + lg * 8);
      acc[ct] = __builtin_amdgcn_mfma_f32_16x16x32_bf16(av, b, acc[ct], 0, 0, 0);
    }
  }
  // ---- svec: s[row] = sum_col acc*a_slice, reduce over 16 l15 lanes ----
  float aS[4], aD[4];
#pragma unroll
  for (int ct = 0; ct < 4; ++ct) {
    aS[ct] = a[ct * 16 + l15];
    aD[ct] = a[64 + ct * 16 + l15];
  }
#pragma unroll
  for (int r = 0; r < 4; ++r) {
    float s1 = acc[0][r] * aS[0] + acc[1][r] * aS[1] + acc[2][r] * aS[2] + acc[3][r] * aS[3];
    float s2 = acc[0][r] * aD[0] + acc[1][r] * aD[1] + acc[2][r] * aD[2] + acc[3][r] * aD[3];
#pragma unroll
    for (int off = 1; off < 16; off <<= 1) {
      s1 += __shfl_xor(s1, off);
      s2 += __shfl_xor(s2, off);
    }
    if (l15 == 0) {
      const int row = m0 + wv * 16 + lg * 4 + r;
      ssrcT[h * 4096 + row] = s1 * LOG2E;
      sdstT[h * 4096 + row] = s2 * LOG2E;
    }
  }
  // ---- transposed bf16 store: WhT[n0+c][m0+m] ----
#pragma unroll
  for (int ct = 0; ct < 4; ++ct)
#pragma unroll
    for (int r = 0; r < 4; ++r)
      tl[(ct * 16 + l15) * 65 + wv * 16 + lg * 4 + r] = acc[ct][r];
  __syncthreads();
  const int c = threadIdx.x >> 2, mb = (threadIdx.x & 3) * 16;
  s16x8 o0, o1;
#pragma unroll
  for (int k = 0; k < 8; ++k) o0[k] = bf16b(tl[c * 65 + mb + k]);
#pragma unroll
  for (int k = 0; k < 8; ++k) o1[k] = bf16b(tl[c * 65 + mb + 8 + k]);
  *(s16x8*)(WhT + (size_t)(n0 + c) * 4096 + m0 + mb) = o0;
  *(s16x8*)(WhT + (size_t)(n0 + c) * 4096 + m0 + mb + 8) = o1;
}

// grid (16 ih x 4 jh, 8 heads) = 512 blocks, 512 thr = 8 waves.
// Block: head h, rows i0b..+255 (wave = 32 rows), j-slice of 1024.
// B-tile [64 cols][64 j] double-buffered in LDS via global_load_lds with
// pre-swizzled source; swizzled read byte = col*128 + ((g ^ (col&7))*16)
// is uniform across bank-quads -> conflict-free. mask/ss staged once.
__global__ __launch_bounds__(512, 4) void k_attn(
    const uint32_t* __restrict__ mask32,
    const ushort* __restrict__ WhT,
    const float* __restrict__ ssrcT,
    const float* __restrict__ sdstT,
    ushort* __restrict__ num,     // [4][4096][512] bf16
    float* __restrict__ lbuf) {   // [4][8][4096]
  __shared__ ushort tile[2][4096];       // 2 x 8 KB
  __shared__ uint32_t mask_s[256 * 36];  // 36.9 KB (stride 36: pad, 16B-aligned)
  __shared__ float ss_s[1024];           // 4 KB

  const int t = threadIdx.x;
  const int lane = t & 63, wv = t >> 6;
  const int l15 = lane & 15, lg = lane >> 4;
  const int h = blockIdx.y;
  const int jh = blockIdx.x & 3;
  const int ih = blockIdx.x >> 2;
  const int i0b = ih * 256;
  const int j0 = jh * 1024;

  // ---- stage ss (1024 f32) ----
  if (t < 256) *(float4*)&ss_s[t * 4] = *(const float4*)(ssrcT + h * 4096 + j0 + t * 4);
  // ---- stage mask: 256 rows x 32 words; 2 threads/row x 64B ----
  {
    const int r = t >> 1, part = t & 1;
    const uint32_t* src = mask32 + (size_t)(i0b + r) * 128 + jh * 32 + part * 16;
    uint32_t* dst = &mask_s[r * 36 + part * 16];
#pragma unroll
    for (int k = 0; k < 4; ++k)
      *(int4*)(dst + k * 4) = *(const int4*)(src + k * 4);
  }
  // ---- per-wave pre-swizzled staging source ----
  const int cg = (wv << 3) + (lane >> 3);       // col 0..63
  const int gg = (lane & 7) ^ (cg & 7);         // j-group 0..7
  const ushort* sbase = WhT + (size_t)(h * 64 + cg) * 4096 + j0 + gg * 8;
  ushort* ldst0 = &tile[0][wv * 512];
  ushort* ldst1 = &tile[1][wv * 512];

  gl_lds16(sbase, ldst0);                       // chunk 0
  __syncthreads();

  const float sd0 = sdstT[h * 4096 + i0b + wv * 32 + l15];
  const float sd1 = sdstT[h * 4096 + i0b + wv * 32 + 16 + l15];
  const int r0loc = wv * 32 + l15;

  f32x4 acc[2][4] = {};
  float lacc0 = 0.f, lacc1 = 0.f;
  int cur = 0;

  for (int c = 0; c < 16; ++c) {
    if (c < 15) gl_lds16(sbase + (c + 1) * 64, cur ? ldst0 : ldst1);
#pragma unroll
    for (int half = 0; half < 2; ++half) {
      const int jsub = half * 32;
      const float4 u = *(const float4*)&ss_s[c * 64 + jsub + lg * 8];
      const float4 v = *(const float4*)&ss_s[c * 64 + jsub + lg * 8 + 4];
      const uint32_t w0 = mask_s[r0loc * 36 + c * 2 + half] >> (lg * 8);
      const uint32_t w1 = mask_s[(r0loc + 16) * 36 + c * 2 + half] >> (lg * 8);
      const char* tb = (const char*)&tile[cur][0];
      s16x8 b[4];
#pragma unroll
      for (int ct = 0; ct < 4; ++ct) {
        const int col = ct * 16 + l15;
        b[ct] = *(const s16x8*)(tb + col * 128 + ((jsub * 2 + lg * 16) ^ ((col & 7) << 4)));
      }
      const float s8[8] = {u.x, u.y, u.z, u.w, v.x, v.y, v.z, v.w};
      s16x8 pa0, pa1;
#pragma unroll
      for (int q = 0; q < 8; ++q) {
        float e0 = sd0 + s8[q]; e0 = fmaxf(e0, 0.2f * e0);
        float x0 = __builtin_amdgcn_exp2f(e0);
        uint32_t m0q = (uint32_t)((int32_t)(w0 << (31 - q)) >> 31);
        float z0 = __uint_as_float(m0q & __float_as_uint(x0));
        lacc0 += z0; pa0[q] = bf16b(z0);
        float e1 = sd1 + s8[q]; e1 = fmaxf(e1, 0.2f * e1);
        float x1 = __builtin_amdgcn_exp2f(e1);
        uint32_t m1q = (uint32_t)((int32_t)(w1 << (31 - q)) >> 31);
        float z1 = __uint_as_float(m1q & __float_as_uint(x1));
        lacc1 += z1; pa1[q] = bf16b(z1);
      }
#pragma unroll
      for (int ct = 0; ct < 4; ++ct) {
        acc[0][ct] = __builtin_amdgcn_mfma_f32_16x16x32_bf16(pa0, b[ct], acc[0][ct], 0, 0, 0);
        acc[1][ct] = __builtin_amdgcn_mfma_f32_16x16x32_bf16(pa1, b[ct], acc[1][ct], 0, 0, 0);
      }
    }
    __syncthreads();
    cur ^= 1;
  }

  // denominator partials: reduce over the 4 lane-groups
  lacc0 += __shfl_xor(lacc0, 16); lacc0 += __shfl_xor(lacc0, 32);
  lacc1 += __shfl_xor(lacc1, 16); lacc1 += __shfl_xor(lacc1, 32);
  if (lane < 16) {
    lbuf[((size_t)jh * 8 + h) * 4096 + i0b + wv * 32 + lane] = lacc0;
    lbuf[((size_t)jh * 8 + h) * 4096 + i0b + wv * 32 + 16 + lane] = lacc1;
  }
  ushort* np = num + (size_t)jh * 4096 * 512;
  const int ibase = i0b + wv * 32;
#pragma unroll
  for (int rt = 0; rt < 2; ++rt)
#pragma unroll
    for (int ct = 0; ct < 4; ++ct)
#pragma unroll
      for (int r = 0; r < 4; ++r)
        np[(size_t)(ibase + rt * 16 + lg * 4 + r) * 512 + h * 64 + ct * 16 + l15] =
            (ushort)bf16b(acc[rt][ct][r]);
}

// 256 blocks x 512 thr; block = 16 rows, thread = 1 col. linv shared via LDS.
__global__ __launch_bounds__(512) void k_stats(const ushort* __restrict__ num,
                                               const float* __restrict__ lbuf,
                                               float* __restrict__ linv,
                                               float* __restrict__ stats) {
  __shared__ float linv_s[128];
  const int t = threadIdx.x;
  const int r0 = blockIdx.x * 16;
  if (t < 128) {
    const int r = r0 + (t >> 3), hh = t & 7;
    float l = 0.f;
#pragma unroll
    for (int s = 0; s < 4; ++s) l += lbuf[((size_t)s * 8 + hh) * 4096 + r];
    const float inv = 1.0f / l;
    linv_s[t] = inv;
    linv[r * 8 + hh] = inv;
  }
  __syncthreads();
  const int c = t;
  const int hh = c >> 6;
  float s1 = 0.f, s2 = 0.f;
  for (int rr = 0; rr < 16; ++rr) {
    const int r = r0 + rr;
    float nsum = 0.f;
#pragma unroll
    for (int s = 0; s < 4; ++s)
      nsum += bf2f(num[(size_t)s * 4096 * 512 + (size_t)r * 512 + c]);
    const float v = nsum * linv_s[rr * 8 + hh];
    s1 += v; s2 += v * v;
  }
  atomicAdd(&stats[c], s1);
  atomicAdd(&stats[512 + c], s2);
}

// 1024 blocks x 256 thr; thread = 8 consecutive cols of one row.
__global__ __launch_bounds__(256) void k_apply(const ushort* __restrict__ num,
                                               const float* __restrict__ linv,
                                               const float* __restrict__ stats,
                                               const float* __restrict__ gamma,
                                               const float* __restrict__ beta,
                                               float* __restrict__ out) {
  const size_t idx8 = ((size_t)blockIdx.x * 256 + threadIdx.x) * 8;
  const int r = (int)(idx8 >> 9);
  const int c0 = (int)(idx8 & 511);
  const float li = linv[r * 8 + (c0 >> 6)];
  float nsum[8] = {};
#pragma unroll
  for (int s = 0; s < 4; ++s) {
    s16x8 nv = *(const s16x8*)(num + (size_t)s * 4096 * 512 + idx8);
#pragma unroll
    for (int k = 0; k < 8; ++k) nsum[k] += bf2f((ushort)nv[k]);
  }
#pragma unroll
  for (int k = 0; k < 8; ++k) {
    const int cc = c0 + k;
    const float mean = stats[cc] * (1.f / 4096.f);
    const float var = stats[512 + cc] * (1.f / 4096.f) - mean * mean;
    const float v = nsum[k] * li;
    const float val = (v - mean) * rsqrtf(var + 1e-5f) * gamma[cc] + beta[cc];
    out[idx8 + k] = fmaxf(val, 0.f);
  }
}

extern "C" void kernel_launch(void* const* d_in, const int* in_sizes, int n_in,
                              void* d_out, int out_size, void* d_ws, size_t ws_size,
                              hipStream_t stream) {
  const float* x = (const float*)d_in[0];
  const int* adj = (const int*)d_in[1];
  const float* W = (const float*)d_in[2];
  const float* a = (const float*)d_in[3];
  const float* gamma = (const float*)d_in[4];
  const float* beta = (const float*)d_in[5];
  float* out = (float*)d_out;

  char* ws = (char*)d_ws;
  size_t off = 0;
  auto alloc = [&](size_t bytes) -> void* {
    void* p = ws + off;
    off += (bytes + 255) & ~(size_t)255;
    return p;
  };
  // persistent region (~7 MB)
  ushort* WhT   = (ushort*)alloc((size_t)512 * 4096 * 2);
  float*  ssrcT = (float*)alloc((size_t)8 * 4096 * 4);
  float*  sdstT = (float*)alloc((size_t)8 * 4096 * 4);
  unsigned long long* maskw = (unsigned long long*)alloc((size_t)4096 * 64 * 8);
  float*  lbuf  = (float*)alloc((size_t)32 * 4096 * 4);
  float*  linv  = (float*)alloc((size_t)4096 * 8 * 4);
  float*  stats = (float*)alloc((size_t)1024 * 4);
  // overlay region: xb+wb (gemm inputs) aliased by num (attn output)
  const size_t ov = off;
  ushort* xb = (ushort*)(ws + ov);
  ushort* wb = (ushort*)(ws + ov + (size_t)4096 * 512 * 2);
  ushort* num = (ushort*)(ws + ov);           // [4][4096][512] bf16 = 16.8 MB
  // total ~24 MB

  hipLaunchKernelGGL(k_convert, dim3(2304), dim3(256), 0, stream, x, W, xb, wb);
  hipLaunchKernelGGL(k_pack, dim3(2048), dim3(256), 0, stream, adj, maskw, stats);
  hipLaunchKernelGGL(k_gemm, dim3(64, 8), dim3(256), 0, stream, xb, wb, a, WhT, ssrcT, sdstT);
  hipLaunchKernelGGL(k_attn, dim3(64, 8), dim3(512), 0, stream,
                     (const uint32_t*)maskw, WhT, ssrcT, sdstT, num, lbuf);
  hipLaunchKernelGGL(k_stats, dim3(256), dim3(512), 0, stream, num, lbuf, linv, stats);
  hipLaunchKernelGGL(k_apply, dim3(1024), dim3(256), 0, stream, num, linv, stats, gamma, beta, out);
}

// Round 6
// 104.913 us; speedup vs baseline: 2.1337x; 1.0182x over previous
//
#include <hip/hip_runtime.h>
#include <hip/hip_bf16.h>
#include <stdint.h>

// GATv2-style layer, MI355X. 6 kernels:
//  k_convert: x,W fp32 -> bf16
//  k_pack:    adj int32 -> bitmask (2 MB) + zero stats
//  k_gemm:    Wh = x @ W^T (bf16 MFMA) -> WhT bf16 (LDS transpose) + s_src/s_dst
//  k_attn:    fused masked-softmax numer/denom + PV MFMA.
//             Block = 1 head x 128 rows x 1024-j slice; wave = 16 rows.
//             All operands LDS-staged; B-tile double-buffered (global_load_lds,
//             pre-swizzled source). Denominator via ones-column MFMA (accd).
//             Target <=64 regs/wave (16+4 acc) -> 8 waves/SIMD, 4 blocks/CU.
//  k_stats:   column sums of h' = (sum num)/(sum l) via atomics; writes linv
//  k_apply:   recompute h', apply layernorm + relu
// num (16.8 MB, bf16, 4 j-slices) aliases xb/wb which are dead after k_gemm.

typedef __attribute__((ext_vector_type(4))) float f32x4;
typedef __attribute__((ext_vector_type(8))) short s16x8;

#define LOG2E 1.4426950408889634f

static __device__ __forceinline__ ushort f2bf(float f) {
  union { float f; uint32_t u; } v; v.f = f;
  uint32_t r = (v.u + 0x7FFFu + ((v.u >> 16) & 1u)) >> 16;  // RNE
  return (ushort)r;
}

static __device__ __forceinline__ short bf16b(float f) {
  __hip_bfloat16 h = __float2bfloat16(f);
  union { __hip_bfloat16 h; short s; } c; c.h = h;
  return c.s;
}

static __device__ __forceinline__ float bf2f(ushort u) {
  union { uint32_t u; float f; } c; c.u = ((uint32_t)u) << 16;
  return c.f;
}

// async global->LDS, 16B per lane; dest = wave-uniform base + lane*16
static __device__ __forceinline__ void gl_lds16(const ushort* g, ushort* l) {
  __builtin_amdgcn_global_load_lds(
      (const __attribute__((address_space(1))) unsigned int*)(g),
      (__attribute__((address_space(3))) unsigned int*)(l), 16, 0, 0);
}

__global__ __launch_bounds__(256) void k_convert(const float* __restrict__ x,
                                                 const float* __restrict__ W,
                                                 ushort* __restrict__ xb,
                                                 ushort* __restrict__ wb) {
  const int idx = (blockIdx.x * 256 + threadIdx.x) * 4;
  const int NX = 4096 * 512;
  if (idx < NX) {
    float4 v = *(const float4*)(x + idx);
    ushort4 o; o.x = f2bf(v.x); o.y = f2bf(v.y); o.z = f2bf(v.z); o.w = f2bf(v.w);
    *(ushort4*)(xb + idx) = o;
  } else {
    const int k = idx - NX;
    float4 v = *(const float4*)(W + k);
    ushort4 o; o.x = f2bf(v.x); o.y = f2bf(v.y); o.z = f2bf(v.z); o.w = f2bf(v.w);
    *(ushort4*)(wb + k) = o;
  }
}

// adj[4096][4096] int32 -> maskw[4096*64] u64 (bit j&63 of word j>>6); zero stats.
__global__ __launch_bounds__(256) void k_pack(const int* __restrict__ adj,
                                              unsigned long long* __restrict__ maskw,
                                              float* __restrict__ stats) {
  const int t = threadIdx.x;
  if (blockIdx.x == 0) {
    stats[t] = 0.f; stats[t + 256] = 0.f; stats[t + 512] = 0.f; stats[t + 768] = 0.f;
  }
  const size_t base = (size_t)blockIdx.x * 8192;
  const int lane = t & 63;
#pragma unroll 4
  for (int it = 0; it < 32; ++it) {
    const size_t elem = base + it * 256 + t;
    unsigned long long b = __ballot(adj[elem] > 0);
    if (lane == 0) maskw[elem >> 6] = b;
  }
}

// Per block: 64 rows (m0) x one head's 64 cols. K=512 direct-global MFMA.
// Epilogue: s_src/s_dst via shfl_xor reduce; WhT bf16 via LDS transpose.
__global__ __launch_bounds__(256) void k_gemm(const ushort* __restrict__ xb,
                                              const ushort* __restrict__ wb,
                                              const float* __restrict__ a,
                                              ushort* __restrict__ WhT,
                                              float* __restrict__ ssrcT,
                                              float* __restrict__ sdstT) {
  __shared__ float tl[64 * 65];
  const int lane = threadIdx.x & 63;
  const int wv = threadIdx.x >> 6;       // 4 waves: M sub-tiles
  const int l15 = lane & 15, lg = lane >> 4;
  const int m0 = blockIdx.x * 64;
  const int h = blockIdx.y;
  const int n0 = h * 64;
  const ushort* ap = xb + (size_t)(m0 + wv * 16 + l15) * 512 + lg * 8;
  f32x4 acc[4] = {};
  for (int k0 = 0; k0 < 512; k0 += 32) {
    s16x8 av = *(const s16x8*)(ap + k0);
#pragma unroll
    for (int ct = 0; ct < 4; ++ct) {
      s16x8 b = *(const s16x8*)(wb + (size_t)(n0 + ct * 16 + l15) * 512 + k0 + lg * 8);
      acc[ct] = __builtin_amdgcn_mfma_f32_16x16x32_bf16(av, b, acc[ct], 0, 0, 0);
    }
  }
  // ---- svec: s[row] = sum_col acc*a_slice, reduce over 16 l15 lanes ----
  float aS[4], aD[4];
#pragma unroll
  for (int ct = 0; ct < 4; ++ct) {
    aS[ct] = a[ct * 16 + l15];
    aD[ct] = a[64 + ct * 16 + l15];
  }
#pragma unroll
  for (int r = 0; r < 4; ++r) {
    float s1 = acc[0][r] * aS[0] + acc[1][r] * aS[1] + acc[2][r] * aS[2] + acc[3][r] * aS[3];
    float s2 = acc[0][r] * aD[0] + acc[1][r] * aD[1] + acc[2][r] * aD[2] + acc[3][r] * aD[3];
#pragma unroll
    for (int off = 1; off < 16; off <<= 1) {
      s1 += __shfl_xor(s1, off);
      s2 += __shfl_xor(s2, off);
    }
    if (l15 == 0) {
      const int row = m0 + wv * 16 + lg * 4 + r;
      ssrcT[h * 4096 + row] = s1 * LOG2E;
      sdstT[h * 4096 + row] = s2 * LOG2E;
    }
  }
  // ---- transposed bf16 store: WhT[n0+c][m0+m] ----
#pragma unroll
  for (int ct = 0; ct < 4; ++ct)
#pragma unroll
    for (int r = 0; r < 4; ++r)
      tl[(ct * 16 + l15) * 65 + wv * 16 + lg * 4 + r] = acc[ct][r];
  __syncthreads();
  const int c = threadIdx.x >> 2, mb = (threadIdx.x & 3) * 16;
  s16x8 o0, o1;
#pragma unroll
  for (int k = 0; k < 8; ++k) o0[k] = bf16b(tl[c * 65 + mb + k]);
#pragma unroll
  for (int k = 0; k < 8; ++k) o1[k] = bf16b(tl[c * 65 + mb + 8 + k]);
  *(s16x8*)(WhT + (size_t)(n0 + c) * 4096 + m0 + mb) = o0;
  *(s16x8*)(WhT + (size_t)(n0 + c) * 4096 + m0 + mb + 8) = o1;
}

// grid (32 ih x 4 jh, 8 heads) = 1024 blocks, 512 thr = 8 waves.
// Block: head h, rows i0b..+127 (wave = 16 rows), j-slice of 1024.
// B-tile [64 cols][64 j] double-buffered in LDS via global_load_lds with
// pre-swizzled source; swizzled read is 2-way-conflict-free.
// Denominator: ones-column constant B-frag -> accd row-sums (no lacc VALU).
__global__ __launch_bounds__(512, 8) void k_attn(
    const uint32_t* __restrict__ mask32,
    const ushort* __restrict__ WhT,
    const float* __restrict__ ssrcT,
    const float* __restrict__ sdstT,
    ushort* __restrict__ num,     // [4][4096][512] bf16
    float* __restrict__ lbuf) {   // [4][8][4096]
  __shared__ ushort tile[2][4096];       // 2 x 8 KB
  __shared__ uint32_t mask_s[128 * 36];  // 18.4 KB (stride 36: 2-way free)
  __shared__ float ss_s[1024];           // 4 KB

  const int t = threadIdx.x;
  const int lane = t & 63, wv = t >> 6;
  const int l15 = lane & 15, lg = lane >> 4;
  const int h = blockIdx.y;
  const int jh = blockIdx.x & 3;
  const int ih = blockIdx.x >> 2;
  const int i0b = ih * 128;
  const int j0 = jh * 1024;

  // ---- stage ss (1024 f32) ----
  if (t < 256) *(float4*)&ss_s[t * 4] = *(const float4*)(ssrcT + h * 4096 + j0 + t * 4);
  // ---- stage mask: 128 rows x 32 words; 4 threads/row x 32B ----
  {
    const int r = t >> 2, part = t & 3;
    const uint32_t* src = mask32 + (size_t)(i0b + r) * 128 + jh * 32 + part * 8;
    uint32_t* dst = &mask_s[r * 36 + part * 8];
    *(int4*)(dst) = *(const int4*)(src);
    *(int4*)(dst + 4) = *(const int4*)(src + 4);
  }
  // ---- per-wave pre-swizzled staging source (wave stages 8 cols) ----
  const int cg = (wv << 3) + (lane >> 3);       // col 0..63
  const int gg = (lane & 7) ^ (cg & 7);         // swizzled j-group
  const ushort* sbase = WhT + (size_t)(h * 64 + cg) * 4096 + j0 + gg * 8;
  ushort* ldst0 = &tile[0][wv * 512];
  ushort* ldst1 = &tile[1][wv * 512];

  gl_lds16(sbase, ldst0);                       // chunk 0
  __syncthreads();

  const int rloc = wv * 16 + l15;
  const float sd = sdstT[h * 4096 + i0b + rloc];

  f32x4 acc[4] = {};
  f32x4 accd = {};
  s16x8 bones;                                  // B ones-column (col 0 = 1.0)
  {
    const short v = (l15 == 0) ? (short)0x3F80 : (short)0;
    bones[0] = v; bones[1] = v; bones[2] = v; bones[3] = v;
    bones[4] = v; bones[5] = v; bones[6] = v; bones[7] = v;
  }
  int cur = 0;

  for (int c = 0; c < 16; ++c) {
    if (c < 15) gl_lds16(sbase + (c + 1) * 64, cur ? ldst0 : ldst1);
#pragma unroll
    for (int half = 0; half < 2; ++half) {
      const int jsub = half * 32;
      const float4 u = *(const float4*)&ss_s[c * 64 + jsub + lg * 8];
      const float4 v = *(const float4*)&ss_s[c * 64 + jsub + lg * 8 + 4];
      const uint32_t w0 = mask_s[rloc * 36 + c * 2 + half] >> (lg * 8);
      const char* tb = (const char*)&tile[cur][0];
      s16x8 b[4];
#pragma unroll
      for (int ct = 0; ct < 4; ++ct) {
        const int col = ct * 16 + l15;
        b[ct] = *(const s16x8*)(tb + col * 128 + ((jsub * 2 + lg * 16) ^ ((col & 7) << 4)));
      }
      const float s8[8] = {u.x, u.y, u.z, u.w, v.x, v.y, v.z, v.w};
      s16x8 pa;
#pragma unroll
      for (int q = 0; q < 8; ++q) {
        float e = sd + s8[q]; e = fmaxf(e, 0.2f * e);
        float xq = __builtin_amdgcn_exp2f(e);
        uint32_t mq = (uint32_t)(((int32_t)(w0 << (31 - q))) >> 31);
        float z = __uint_as_float(mq & __float_as_uint(xq));
        pa[q] = bf16b(z);
      }
      accd = __builtin_amdgcn_mfma_f32_16x16x32_bf16(pa, bones, accd, 0, 0, 0);
#pragma unroll
      for (int ct = 0; ct < 4; ++ct)
        acc[ct] = __builtin_amdgcn_mfma_f32_16x16x32_bf16(pa, b[ct], acc[ct], 0, 0, 0);
    }
    __syncthreads();
    cur ^= 1;
  }

  // denominator partials: lanes l15==0 hold rows lg*4+r at col 0 of accd
  if (l15 == 0) {
#pragma unroll
    for (int r = 0; r < 4; ++r)
      lbuf[((size_t)jh * 8 + h) * 4096 + i0b + wv * 16 + lg * 4 + r] = accd[r];
  }
  ushort* np = num + (size_t)jh * 4096 * 512;
#pragma unroll
  for (int ct = 0; ct < 4; ++ct)
#pragma unroll
    for (int r = 0; r < 4; ++r)
      np[(size_t)(i0b + wv * 16 + lg * 4 + r) * 512 + h * 64 + ct * 16 + l15] =
          (ushort)bf16b(acc[ct][r]);
}

// 256 blocks x 512 thr; block = 16 rows, thread = 1 col. linv shared via LDS.
__global__ __launch_bounds__(512) void k_stats(const ushort* __restrict__ num,
                                               const float* __restrict__ lbuf,
                                               float* __restrict__ linv,
                                               float* __restrict__ stats) {
  __shared__ float linv_s[128];
  const int t = threadIdx.x;
  const int r0 = blockIdx.x * 16;
  if (t < 128) {
    const int r = r0 + (t >> 3), hh = t & 7;
    float l = 0.f;
#pragma unroll
    for (int s = 0; s < 4; ++s) l += lbuf[((size_t)s * 8 + hh) * 4096 + r];
    const float inv = 1.0f / l;
    linv_s[t] = inv;
    linv[r * 8 + hh] = inv;
  }
  __syncthreads();
  const int c = t;
  const int hh = c >> 6;
  float s1 = 0.f, s2 = 0.f;
  for (int rr = 0; rr < 16; ++rr) {
    const int r = r0 + rr;
    float nsum = 0.f;
#pragma unroll
    for (int s = 0; s < 4; ++s)
      nsum += bf2f(num[(size_t)s * 4096 * 512 + (size_t)r * 512 + c]);
    const float v = nsum * linv_s[rr * 8 + hh];
    s1 += v; s2 += v * v;
  }
  atomicAdd(&stats[c], s1);
  atomicAdd(&stats[512 + c], s2);
}

// 1024 blocks x 256 thr; thread = 8 consecutive cols of one row.
__global__ __launch_bounds__(256) void k_apply(const ushort* __restrict__ num,
                                               const float* __restrict__ linv,
                                               const float* __restrict__ stats,
                                               const float* __restrict__ gamma,
                                               const float* __restrict__ beta,
                                               float* __restrict__ out) {
  const size_t idx8 = ((size_t)blockIdx.x * 256 + threadIdx.x) * 8;
  const int r = (int)(idx8 >> 9);
  const int c0 = (int)(idx8 & 511);
  const float li = linv[r * 8 + (c0 >> 6)];
  float nsum[8] = {};
#pragma unroll
  for (int s = 0; s < 4; ++s) {
    s16x8 nv = *(const s16x8*)(num + (size_t)s * 4096 * 512 + idx8);
#pragma unroll
    for (int k = 0; k < 8; ++k) nsum[k] += bf2f((ushort)nv[k]);
  }
#pragma unroll
  for (int k = 0; k < 8; ++k) {
    const int cc = c0 + k;
    const float mean = stats[cc] * (1.f / 4096.f);
    const float var = stats[512 + cc] * (1.f / 4096.f) - mean * mean;
    const float v = nsum[k] * li;
    const float val = (v - mean) * rsqrtf(var + 1e-5f) * gamma[cc] + beta[cc];
    out[idx8 + k] = fmaxf(val, 0.f);
  }
}

extern "C" void kernel_launch(void* const* d_in, const int* in_sizes, int n_in,
                              void* d_out, int out_size, void* d_ws, size_t ws_size,
                              hipStream_t stream) {
  const float* x = (const float*)d_in[0];
  const int* adj = (const int*)d_in[1];
  const float* W = (const float*)d_in[2];
  const float* a = (const float*)d_in[3];
  const float* gamma = (const float*)d_in[4];
  const float* beta = (const float*)d_in[5];
  float* out = (float*)d_out;

  char* ws = (char*)d_ws;
  size_t off = 0;
  auto alloc = [&](size_t bytes) -> void* {
    void* p = ws + off;
    off += (bytes + 255) & ~(size_t)255;
    return p;
  };
  // persistent region (~7 MB)
  ushort* WhT   = (ushort*)alloc((size_t)512 * 4096 * 2);
  float*  ssrcT = (float*)alloc((size_t)8 * 4096 * 4);
  float*  sdstT = (float*)alloc((size_t)8 * 4096 * 4);
  unsigned long long* maskw = (unsigned long long*)alloc((size_t)4096 * 64 * 8);
  float*  lbuf  = (float*)alloc((size_t)32 * 4096 * 4);
  float*  linv  = (float*)alloc((size_t)4096 * 8 * 4);
  float*  stats = (float*)alloc((size_t)1024 * 4);
  // overlay region: xb+wb (gemm inputs) aliased by num (attn output)
  const size_t ov = off;
  ushort* xb = (ushort*)(ws + ov);
  ushort* wb = (ushort*)(ws + ov + (size_t)4096 * 512 * 2);
  ushort* num = (ushort*)(ws + ov);           // [4][4096][512] bf16 = 16.8 MB
  // total ~24 MB

  hipLaunchKernelGGL(k_convert, dim3(2304), dim3(256), 0, stream, x, W, xb, wb);
  hipLaunchKernelGGL(k_pack, dim3(2048), dim3(256), 0, stream, adj, maskw, stats);
  hipLaunchKernelGGL(k_gemm, dim3(64, 8), dim3(256), 0, stream, xb, wb, a, WhT, ssrcT, sdstT);
  hipLaunchKernelGGL(k_attn, dim3(128, 8), dim3(512), 0, stream,
                     (const uint32_t*)maskw, WhT, ssrcT, sdstT, num, lbuf);
  hipLaunchKernelGGL(k_stats, dim3(256), dim3(512), 0, stream, num, lbuf, linv, stats);
  hipLaunchKernelGGL(k_apply, dim3(1024), dim3(256), 0, stream, num, linv, stats, gamma, beta, out);
}

// Round 7
// 92.753 us; speedup vs baseline: 2.4135x; 1.1311x over previous
//
#include <hip/hip_runtime.h>
#include <hip/hip_bf16.h>
#include <stdint.h>

// GATv2-style layer, MI355X. 6 kernels:
//  k_convert: x,W fp32 -> bf16
//  k_pack:    adj int32 -> bitmask (2 MB) + zero stats
//  k_gemm:    Wh = x @ W^T (bf16 MFMA, B-tile LDS-staged w/ XOR swizzle)
//             -> WhT bf16 (LDS transpose, aliased buffer) + s_src/s_dst
//  k_attn:    fused masked-softmax numer/denom + PV MFMA.
//             Block = 1 head x 256 rows x 1024-j slice; wave = 32 rows
//             (B-frag LDS reads amortized over 2 row-tiles -> 6.3 B/elem).
//             bf16 conversion paired via v_cvt_pk_bf16_f32.
//             Denominator via ones-column MFMA.
//  k_stats:   column sums of h' = (sum num)/(sum l) via atomics; writes linv
//  k_apply:   recompute h', apply layernorm + relu
// num (16.8 MB, bf16, 4 j-slices) aliases xb/wb which are dead after k_gemm.

typedef __attribute__((ext_vector_type(4))) float f32x4;
typedef __attribute__((ext_vector_type(8))) short s16x8;

#define LOG2E 1.4426950408889634f

static __device__ __forceinline__ ushort f2bf(float f) {
  union { float f; uint32_t u; } v; v.f = f;
  uint32_t r = (v.u + 0x7FFFu + ((v.u >> 16) & 1u)) >> 16;  // RNE
  return (ushort)r;
}

static __device__ __forceinline__ short bf16b(float f) {
  __hip_bfloat16 h = __float2bfloat16(f);
  union { __hip_bfloat16 h; short s; } c; c.h = h;
  return c.s;
}

static __device__ __forceinline__ float bf2f(ushort u) {
  union { uint32_t u; float f; } c; c.u = ((uint32_t)u) << 16;
  return c.f;
}

// async global->LDS, 16B per lane; dest = wave-uniform base + lane*16
static __device__ __forceinline__ void gl_lds16(const ushort* g, ushort* l) {
  __builtin_amdgcn_global_load_lds(
      (const __attribute__((address_space(1))) unsigned int*)(g),
      (__attribute__((address_space(3))) unsigned int*)(l), 16, 0, 0);
}

__global__ __launch_bounds__(256) void k_convert(const float* __restrict__ x,
                                                 const float* __restrict__ W,
                                                 ushort* __restrict__ xb,
                                                 ushort* __restrict__ wb) {
  const int idx = (blockIdx.x * 256 + threadIdx.x) * 4;
  const int NX = 4096 * 512;
  if (idx < NX) {
    float4 v = *(const float4*)(x + idx);
    ushort4 o; o.x = f2bf(v.x); o.y = f2bf(v.y); o.z = f2bf(v.z); o.w = f2bf(v.w);
    *(ushort4*)(xb + idx) = o;
  } else {
    const int k = idx - NX;
    float4 v = *(const float4*)(W + k);
    ushort4 o; o.x = f2bf(v.x); o.y = f2bf(v.y); o.z = f2bf(v.z); o.w = f2bf(v.w);
    *(ushort4*)(wb + k) = o;
  }
}

// adj[4096][4096] int32 -> maskw[4096*64] u64 (bit j&63 of word j>>6); zero stats.
__global__ __launch_bounds__(256) void k_pack(const int* __restrict__ adj,
                                              unsigned long long* __restrict__ maskw,
                                              float* __restrict__ stats) {
  const int t = threadIdx.x;
  if (blockIdx.x == 0) {
    stats[t] = 0.f; stats[t + 256] = 0.f; stats[t + 512] = 0.f; stats[t + 768] = 0.f;
  }
  const size_t base = (size_t)blockIdx.x * 8192;
  const int lane = t & 63;
#pragma unroll 4
  for (int it = 0; it < 32; ++it) {
    const size_t elem = base + it * 256 + t;
    unsigned long long b = __ballot(adj[elem] > 0);
    if (lane == 0) maskw[elem >> 6] = b;
  }
}

// Per block: 64 rows (m0) x one head's 64 cols. K=512.
// B-tile (64 cols x 512 K = 64 KB) LDS-staged via global_load_lds with
// pre-swizzled source (same XOR scheme as k_attn, 1 KB col-rows).
// A direct-global (16 independent pipelined b128 loads).
// Epilogue: s_src/s_dst via shfl_xor reduce; WhT bf16 via LDS transpose
// (transpose buffer aliases the B-tile).
__global__ __launch_bounds__(256) void k_gemm(const ushort* __restrict__ xb,
                                              const ushort* __restrict__ wb,
                                              const float* __restrict__ a,
                                              ushort* __restrict__ WhT,
                                              float* __restrict__ ssrcT,
                                              float* __restrict__ sdstT) {
  __shared__ ushort bt[64 * 512];        // 64 KB; later aliased as f32 tl[64*65]
  float* tl = (float*)bt;
  const int lane = threadIdx.x & 63;
  const int wv = threadIdx.x >> 6;       // 4 waves: M sub-tiles
  const int l15 = lane & 15, lg = lane >> 4;
  const int m0 = blockIdx.x * 64;
  const int h = blockIdx.y;
  const int n0 = h * 64;

  // ---- stage B: wave wv stages cols it*4+wv (1 KB each, swizzled source) ----
#pragma unroll
  for (int it = 0; it < 16; ++it) {
    const int col = it * 4 + wv;
    const ushort* src = wb + (size_t)(n0 + col) * 512 + (lane ^ (col & 7)) * 8;
    gl_lds16(src, &bt[col * 512]);
  }
  __syncthreads();

  const ushort* ap = xb + (size_t)(m0 + wv * 16 + l15) * 512 + lg * 8;
  f32x4 acc[4] = {};
  for (int k0 = 0; k0 < 512; k0 += 32) {
    s16x8 av = *(const s16x8*)(ap + k0);
#pragma unroll
    for (int ct = 0; ct < 4; ++ct) {
      const int col = ct * 16 + l15;
      s16x8 b = *(const s16x8*)((const char*)bt + col * 1024 +
                                (((k0 + lg * 8) * 2) ^ ((col & 7) << 4)));
      acc[ct] = __builtin_amdgcn_mfma_f32_16x16x32_bf16(av, b, acc[ct], 0, 0, 0);
    }
  }
  // ---- svec: s[row] = sum_col acc*a_slice, reduce over 16 l15 lanes ----
  float aS[4], aD[4];
#pragma unroll
  for (int ct = 0; ct < 4; ++ct) {
    aS[ct] = a[ct * 16 + l15];
    aD[ct] = a[64 + ct * 16 + l15];
  }
#pragma unroll
  for (int r = 0; r < 4; ++r) {
    float s1 = acc[0][r] * aS[0] + acc[1][r] * aS[1] + acc[2][r] * aS[2] + acc[3][r] * aS[3];
    float s2 = acc[0][r] * aD[0] + acc[1][r] * aD[1] + acc[2][r] * aD[2] + acc[3][r] * aD[3];
#pragma unroll
    for (int off = 1; off < 16; off <<= 1) {
      s1 += __shfl_xor(s1, off);
      s2 += __shfl_xor(s2, off);
    }
    if (l15 == 0) {
      const int row = m0 + wv * 16 + lg * 4 + r;
      ssrcT[h * 4096 + row] = s1 * LOG2E;
      sdstT[h * 4096 + row] = s2 * LOG2E;
    }
  }
  // ---- transposed bf16 store: WhT[n0+c][m0+m] (tl aliases bt; barrier first) ----
  __syncthreads();
#pragma unroll
  for (int ct = 0; ct < 4; ++ct)
#pragma unroll
    for (int r = 0; r < 4; ++r)
      tl[(ct * 16 + l15) * 65 + wv * 16 + lg * 4 + r] = acc[ct][r];
  __syncthreads();
  const int c = threadIdx.x >> 2, mb = (threadIdx.x & 3) * 16;
  s16x8 o0, o1;
#pragma unroll
  for (int k = 0; k < 8; ++k) o0[k] = bf16b(tl[c * 65 + mb + k]);
#pragma unroll
  for (int k = 0; k < 8; ++k) o1[k] = bf16b(tl[c * 65 + mb + 8 + k]);
  *(s16x8*)(WhT + (size_t)(n0 + c) * 4096 + m0 + mb) = o0;
  *(s16x8*)(WhT + (size_t)(n0 + c) * 4096 + m0 + mb + 8) = o1;
}

// grid (16 ih x 4 jh, 8 heads) = 512 blocks, 512 thr = 8 waves.
// Block: head h, rows i0b..+255 (wave = 32 rows = 2 row-tiles), j-slice 1024.
// B-tile [64 cols][64 j] double-buffered via global_load_lds (pre-swizzled
// source); B-frag reads amortized over 2 row-tiles. cvt_pk bf16 pairs.
// Denominator: ones-column constant B-frag -> accd row-sums.
__global__ __launch_bounds__(512, 4) void k_attn(
    const uint32_t* __restrict__ mask32,
    const ushort* __restrict__ WhT,
    const float* __restrict__ ssrcT,
    const float* __restrict__ sdstT,
    ushort* __restrict__ num,     // [4][4096][512] bf16
    float* __restrict__ lbuf) {   // [4][8][4096]
  __shared__ ushort tile[2][4096];       // 16 KB
  __shared__ uint32_t mask_s[256 * 33];  // 33.8 KB (stride 33: conflict-free)
  __shared__ float ss_s[1024];           // 4 KB

  const int t = threadIdx.x;
  const int lane = t & 63, wv = t >> 6;
  const int l15 = lane & 15, lg = lane >> 4;
  const int h = blockIdx.y;
  const int jh = blockIdx.x & 3;
  const int ih = blockIdx.x >> 2;
  const int i0b = ih * 256;
  const int j0 = jh * 1024;

  // ---- stage ss (1024 f32) ----
  if (t < 256) *(float4*)&ss_s[t * 4] = *(const float4*)(ssrcT + h * 4096 + j0 + t * 4);
  // ---- stage mask: 256 rows x 32 words; 2 threads/row x 64B ----
  {
    const int r = t >> 1, part = t & 1;
    const uint32_t* src = mask32 + (size_t)(i0b + r) * 128 + jh * 32 + part * 16;
    uint32_t* dst = &mask_s[r * 33 + part * 16];
#pragma unroll
    for (int k = 0; k < 4; ++k)
      *(int4*)(dst + k * 4) = *(const int4*)(src + k * 4);
  }
  // ---- per-wave pre-swizzled staging source (wave stages 8 cols) ----
  const int cg = (wv << 3) + (lane >> 3);       // col 0..63
  const int gg = (lane & 7) ^ (cg & 7);         // swizzled j-group
  const ushort* sbase = WhT + (size_t)(h * 64 + cg) * 4096 + j0 + gg * 8;
  ushort* ldst0 = &tile[0][wv * 512];
  ushort* ldst1 = &tile[1][wv * 512];

  gl_lds16(sbase, ldst0);                       // chunk 0
  __syncthreads();

  const int rloc = wv * 32 + l15;
  const float sd0 = sdstT[h * 4096 + i0b + rloc];
  const float sd1 = sdstT[h * 4096 + i0b + rloc + 16];

  f32x4 acc[2][4] = {};
  f32x4 accd0 = {}, accd1 = {};
  s16x8 bones;                                  // B ones-column (col 0 = 1.0)
  {
    const short v = (l15 == 0) ? (short)0x3F80 : (short)0;
    bones[0] = v; bones[1] = v; bones[2] = v; bones[3] = v;
    bones[4] = v; bones[5] = v; bones[6] = v; bones[7] = v;
  }
  int cur = 0;

  for (int c = 0; c < 16; ++c) {
    if (c < 15) gl_lds16(sbase + (c + 1) * 64, cur ? ldst0 : ldst1);
#pragma unroll
    for (int half = 0; half < 2; ++half) {
      const int jsub = half * 32;
      const float4 u = *(const float4*)&ss_s[c * 64 + jsub + lg * 8];
      const float4 v = *(const float4*)&ss_s[c * 64 + jsub + lg * 8 + 4];
      const uint32_t w0 = mask_s[rloc * 33 + c * 2 + half] >> (lg * 8);
      const uint32_t w1 = mask_s[(rloc + 16) * 33 + c * 2 + half] >> (lg * 8);
      const char* tb = (const char*)&tile[cur][0];
      s16x8 b[4];
#pragma unroll
      for (int ct = 0; ct < 4; ++ct) {
        const int col = ct * 16 + l15;
        b[ct] = *(const s16x8*)(tb + col * 128 + ((jsub * 2 + lg * 16) ^ ((col & 7) << 4)));
      }
      const float s8[8] = {u.x, u.y, u.z, u.w, v.x, v.y, v.z, v.w};
      union { s16x8 v8; uint32_t u32[4]; } pa0, pa1;
#pragma unroll
      for (int qp = 0; qp < 4; ++qp) {
        float z0[2], z1[2];
#pragma unroll
        for (int k = 0; k < 2; ++k) {
          const int q = qp * 2 + k;
          float e0 = sd0 + s8[q]; e0 = fmaxf(e0, 0.2f * e0);
          float x0 = __builtin_amdgcn_exp2f(e0);
          uint32_t m0 = (uint32_t)(((int32_t)(w0 << (31 - q))) >> 31);
          z0[k] = __uint_as_float(m0 & __float_as_uint(x0));
          float e1 = sd1 + s8[q]; e1 = fmaxf(e1, 0.2f * e1);
          float x1 = __builtin_amdgcn_exp2f(e1);
          uint32_t m1 = (uint32_t)(((int32_t)(w1 << (31 - q))) >> 31);
          z1[k] = __uint_as_float(m1 & __float_as_uint(x1));
        }
        union { __hip_bfloat162 h2; uint32_t u; } c0, c1;
        c0.h2 = __float22bfloat162_rn(make_float2(z0[0], z0[1]));
        c1.h2 = __float22bfloat162_rn(make_float2(z1[0], z1[1]));
        pa0.u32[qp] = c0.u;
        pa1.u32[qp] = c1.u;
      }
      accd0 = __builtin_amdgcn_mfma_f32_16x16x32_bf16(pa0.v8, bones, accd0, 0, 0, 0);
      accd1 = __builtin_amdgcn_mfma_f32_16x16x32_bf16(pa1.v8, bones, accd1, 0, 0, 0);
#pragma unroll
      for (int ct = 0; ct < 4; ++ct) {
        acc[0][ct] = __builtin_amdgcn_mfma_f32_16x16x32_bf16(pa0.v8, b[ct], acc[0][ct], 0, 0, 0);
        acc[1][ct] = __builtin_amdgcn_mfma_f32_16x16x32_bf16(pa1.v8, b[ct], acc[1][ct], 0, 0, 0);
      }
    }
    __syncthreads();
    cur ^= 1;
  }

  // denominator partials: lanes l15==0 hold rows lg*4+r at col 0 of accd
  if (l15 == 0) {
    float* lb = &lbuf[((size_t)jh * 8 + h) * 4096 + i0b + rloc];  // rloc has l15=0
#pragma unroll
    for (int r = 0; r < 4; ++r) lb[lg * 4 + r] = accd0[r];
#pragma unroll
    for (int r = 0; r < 4; ++r) lb[16 + lg * 4 + r] = accd1[r];
  }
  ushort* np = num + (size_t)jh * 4096 * 512;
#pragma unroll
  for (int rs = 0; rs < 2; ++rs)
#pragma unroll
    for (int ct = 0; ct < 4; ++ct)
#pragma unroll
      for (int r = 0; r < 4; ++r)
        np[(size_t)(i0b + wv * 32 + rs * 16 + lg * 4 + r) * 512 + h * 64 + ct * 16 + l15] =
            (ushort)bf16b(acc[rs][ct][r]);
}

// 256 blocks x 512 thr; block = 16 rows, thread = 1 col. linv shared via LDS.
__global__ __launch_bounds__(512) void k_stats(const ushort* __restrict__ num,
                                               const float* __restrict__ lbuf,
                                               float* __restrict__ linv,
                                               float* __restrict__ stats) {
  __shared__ float linv_s[128];
  const int t = threadIdx.x;
  const int r0 = blockIdx.x * 16;
  if (t < 128) {
    const int r = r0 + (t >> 3), hh = t & 7;
    float l = 0.f;
#pragma unroll
    for (int s = 0; s < 4; ++s) l += lbuf[((size_t)s * 8 + hh) * 4096 + r];
    const float inv = 1.0f / l;
    linv_s[t] = inv;
    linv[r * 8 + hh] = inv;
  }
  __syncthreads();
  const int c = t;
  const int hh = c >> 6;
  float s1 = 0.f, s2 = 0.f;
  for (int rr = 0; rr < 16; ++rr) {
    const int r = r0 + rr;
    float nsum = 0.f;
#pragma unroll
    for (int s = 0; s < 4; ++s)
      nsum += bf2f(num[(size_t)s * 4096 * 512 + (size_t)r * 512 + c]);
    const float v = nsum * linv_s[rr * 8 + hh];
    s1 += v; s2 += v * v;
  }
  atomicAdd(&stats[c], s1);
  atomicAdd(&stats[512 + c], s2);
}

// 1024 blocks x 256 thr; thread = 8 consecutive cols of one row.
__global__ __launch_bounds__(256) void k_apply(const ushort* __restrict__ num,
                                               const float* __restrict__ linv,
                                               const float* __restrict__ stats,
                                               const float* __restrict__ gamma,
                                               const float* __restrict__ beta,
                                               float* __restrict__ out) {
  const size_t idx8 = ((size_t)blockIdx.x * 256 + threadIdx.x) * 8;
  const int r = (int)(idx8 >> 9);
  const int c0 = (int)(idx8 & 511);
  const float li = linv[r * 8 + (c0 >> 6)];
  float nsum[8] = {};
#pragma unroll
  for (int s = 0; s < 4; ++s) {
    s16x8 nv = *(const s16x8*)(num + (size_t)s * 4096 * 512 + idx8);
#pragma unroll
    for (int k = 0; k < 8; ++k) nsum[k] += bf2f((ushort)nv[k]);
  }
#pragma unroll
  for (int k = 0; k < 8; ++k) {
    const int cc = c0 + k;
    const float mean = stats[cc] * (1.f / 4096.f);
    const float var = stats[512 + cc] * (1.f / 4096.f) - mean * mean;
    const float v = nsum[k] * li;
    const float val = (v - mean) * rsqrtf(var + 1e-5f) * gamma[cc] + beta[cc];
    out[idx8 + k] = fmaxf(val, 0.f);
  }
}

extern "C" void kernel_launch(void* const* d_in, const int* in_sizes, int n_in,
                              void* d_out, int out_size, void* d_ws, size_t ws_size,
                              hipStream_t stream) {
  const float* x = (const float*)d_in[0];
  const int* adj = (const int*)d_in[1];
  const float* W = (const float*)d_in[2];
  const float* a = (const float*)d_in[3];
  const float* gamma = (const float*)d_in[4];
  const float* beta = (const float*)d_in[5];
  float* out = (float*)d_out;

  char* ws = (char*)d_ws;
  size_t off = 0;
  auto alloc = [&](size_t bytes) -> void* {
    void* p = ws + off;
    off += (bytes + 255) & ~(size_t)255;
    return p;
  };
  // persistent region (~7 MB)
  ushort* WhT   = (ushort*)alloc((size_t)512 * 4096 * 2);
  float*  ssrcT = (float*)alloc((size_t)8 * 4096 * 4);
  float*  sdstT = (float*)alloc((size_t)8 * 4096 * 4);
  unsigned long long* maskw = (unsigned long long*)alloc((size_t)4096 * 64 * 8);
  float*  lbuf  = (float*)alloc((size_t)32 * 4096 * 4);
  float*  linv  = (float*)alloc((size_t)4096 * 8 * 4);
  float*  stats = (float*)alloc((size_t)1024 * 4);
  // overlay region: xb+wb (gemm inputs) aliased by num (attn output)
  const size_t ov = off;
  ushort* xb = (ushort*)(ws + ov);
  ushort* wb = (ushort*)(ws + ov + (size_t)4096 * 512 * 2);
  ushort* num = (ushort*)(ws + ov);           // [4][4096][512] bf16 = 16.8 MB
  // total ~24 MB

  hipLaunchKernelGGL(k_convert, dim3(2304), dim3(256), 0, stream, x, W, xb, wb);
  hipLaunchKernelGGL(k_pack, dim3(2048), dim3(256), 0, stream, adj, maskw, stats);
  hipLaunchKernelGGL(k_gemm, dim3(64, 8), dim3(256), 0, stream, xb, wb, a, WhT, ssrcT, sdstT);
  hipLaunchKernelGGL(k_attn, dim3(64, 8), dim3(512), 0, stream,
                     (const uint32_t*)maskw, WhT, ssrcT, sdstT, num, lbuf);
  hipLaunchKernelGGL(k_stats, dim3(256), dim3(512), 0, stream, num, lbuf, linv, stats);
  hipLaunchKernelGGL(k_apply, dim3(1024), dim3(256), 0, stream, num, linv, stats, gamma, beta, out);
}